// Round 2
// baseline (15633.121 us; speedup 1.0000x reference)
//
#include <hip/hip_runtime.h>
#include <hip/hip_fp16.h>

#define TT 30
#define BATCH 8192

__device__ __forceinline__ float sigf(float x) { return 1.0f / (1.0f + __expf(-x)); }

// storage-type helpers (fp32 or fp16 intermediate tensors)
__device__ __forceinline__ void ld4(const float* p, float* d) { *(float4*)d = *(const float4*)p; }
__device__ __forceinline__ void ld4(const __half* p, float* d) {
    const __half2 a = *(const __half2*)p;
    const __half2 b = *(const __half2*)(p + 2);
    const float2 fa = __half22float2(a), fb = __half22float2(b);
    d[0] = fa.x; d[1] = fa.y; d[2] = fb.x; d[3] = fb.y;
}
__device__ __forceinline__ void st1(float* p, float v)  { *p = v; }
__device__ __forceinline__ void st1(__half* p, float v) { *p = __float2half(v); }

// ---------------------------------------------------------------------------
// Fused bidirectional LSTM layer. Each block owns RB batch rows for ONE
// direction, iterates all TT steps. h kept in LDS (single buffer, 2
// barriers/step; new h held in regs between barriers). c in registers.
// Gate order per reference: i,f,g,o; c = sig(f)*c + sig(i)*relu(g);
// h = sig(o)*relu(c).
// If FUSE: instead of writing h3 to global, do the per-step rank-U update of
// dense1 (d1_partial[32x256] += h_t @ d1w_slice) and atomicAdd at the end.
// ---------------------------------------------------------------------------
template<int DIN, int U, int RB, bool FUSE, typename TIN, typename TOUT>
__global__ __launch_bounds__(256, 2)
void lstm_k(const TIN* __restrict__ x,
            const float* __restrict__ wf, const float* __restrict__ uf, const float* __restrict__ bfp,
            const float* __restrict__ wb, const float* __restrict__ ub, const float* __restrict__ bbp,
            TOUT* __restrict__ out,
            const float* __restrict__ d1w,
            float* __restrict__ d1o)
{
    constexpr int CC  = U / 64;   // 64-col chunks, one lane each
    constexpr int RPG = RB / 4;   // rows per wave (4 waves)
    static_assert(!FUSE || (U == 256 && RB == 32), "fused path is lstm3-specific");

    const int dir = blockIdx.y;
    const float* __restrict__ W    = dir ? wb  : wf;
    const float* __restrict__ Uw   = dir ? ub  : uf;
    const float* __restrict__ bias = dir ? bbp : bfp;

    const int lane  = threadIdx.x & 63;
    const int wv    = threadIdx.x >> 6;
    const int rloc0 = wv * RPG;
    const int row0  = blockIdx.x * RB;

    __shared__ float hbuf[RB][U];   // 32 KB max (lstm3)

    float creg[CC][RPG];
#pragma unroll
    for (int a = 0; a < CC; ++a)
#pragma unroll
        for (int r = 0; r < RPG; ++r) creg[a][r] = 0.0f;

    float acc1[FUSE ? RPG : 1][4];
#pragma unroll
    for (int r = 0; r < (FUSE ? RPG : 1); ++r)
#pragma unroll
        for (int q = 0; q < 4; ++q) acc1[r][q] = 0.0f;

    for (int i = threadIdx.x; i < RB * U; i += 256)
        (&hbuf[0][0])[i] = 0.0f;   // h0 = 0

    float bI[CC], bF[CC], bG[CC], bO[CC];
#pragma unroll
    for (int a = 0; a < CC; ++a) {
        const int j = a * 64 + lane;
        bI[a] = bias[0 * U + j];
        bF[a] = bias[1 * U + j];
        bG[a] = bias[2 * U + j];
        bO[a] = bias[3 * U + j];
    }

    __syncthreads();

#pragma unroll 1
    for (int s = 0; s < TT; ++s) {
        const int t = dir ? (TT - 1 - s) : s;
        float hnew[CC][RPG];

#pragma unroll 1
        for (int a = 0; a < CC; ++a) {
            const int j = a * 64 + lane;
            float aI[RPG], aF[RPG], aG[RPG], aO[RPG];
#pragma unroll
            for (int r = 0; r < RPG; ++r) {
                aI[r] = bI[a]; aF[r] = bF[a]; aG[r] = bG[a]; aO[r] = bO[a];
            }

            // ---- input contribution: z += x_t @ W ----
            if constexpr ((DIN % 4) == 0) {
#pragma unroll 2
                for (int k = 0; k < DIN; k += 4) {
                    float wI[4], wF[4], wG[4], wO[4];
#pragma unroll
                    for (int q = 0; q < 4; ++q) {
                        const float* wr = W + (size_t)(k + q) * (4 * U) + j;
                        wI[q] = wr[0];     wF[q] = wr[U];
                        wG[q] = wr[2 * U]; wO[q] = wr[3 * U];
                    }
#pragma unroll
                    for (int r = 0; r < RPG; ++r) {
                        float xv[4];
                        ld4(x + ((size_t)(row0 + rloc0 + r) * TT + t) * DIN + k, xv);
#pragma unroll
                        for (int q = 0; q < 4; ++q) {
                            aI[r] = fmaf(xv[q], wI[q], aI[r]);
                            aF[r] = fmaf(xv[q], wF[q], aF[r]);
                            aG[r] = fmaf(xv[q], wG[q], aG[r]);
                            aO[r] = fmaf(xv[q], wO[q], aO[r]);
                        }
                    }
                }
            } else {
                // DIN==126 (layer 1 only; TIN is float there) -> float2 loads
#pragma unroll 2
                for (int k = 0; k < DIN; k += 2) {
                    float wI[2], wF[2], wG[2], wO[2];
#pragma unroll
                    for (int q = 0; q < 2; ++q) {
                        const float* wr = W + (size_t)(k + q) * (4 * U) + j;
                        wI[q] = wr[0];     wF[q] = wr[U];
                        wG[q] = wr[2 * U]; wO[q] = wr[3 * U];
                    }
#pragma unroll
                    for (int r = 0; r < RPG; ++r) {
                        float xv[2];
                        *(float2*)xv = *(const float2*)((const float*)x + ((size_t)(row0 + rloc0 + r) * TT + t) * DIN + k);
#pragma unroll
                        for (int q = 0; q < 2; ++q) {
                            aI[r] = fmaf(xv[q], wI[q], aI[r]);
                            aF[r] = fmaf(xv[q], wF[q], aF[r]);
                            aG[r] = fmaf(xv[q], wG[q], aG[r]);
                            aO[r] = fmaf(xv[q], wO[q], aO[r]);
                        }
                    }
                }
            }

            // ---- recurrent contribution: z += h @ Uw ----
#pragma unroll 2
            for (int k = 0; k < U; k += 4) {
                float wI[4], wF[4], wG[4], wO[4];
#pragma unroll
                for (int q = 0; q < 4; ++q) {
                    const float* ur = Uw + (size_t)(k + q) * (4 * U) + j;
                    wI[q] = ur[0];     wF[q] = ur[U];
                    wG[q] = ur[2 * U]; wO[q] = ur[3 * U];
                }
#pragma unroll
                for (int r = 0; r < RPG; ++r) {
                    float hv[4];
                    *(float4*)hv = *(const float4*)(&hbuf[rloc0 + r][k]);
#pragma unroll
                    for (int q = 0; q < 4; ++q) {
                        aI[r] = fmaf(hv[q], wI[q], aI[r]);
                        aF[r] = fmaf(hv[q], wF[q], aF[r]);
                        aG[r] = fmaf(hv[q], wG[q], aG[r]);
                        aO[r] = fmaf(hv[q], wO[q], aO[r]);
                    }
                }
            }

            // ---- gates / state update (hold h in regs; LDS write after barrier)
#pragma unroll
            for (int r = 0; r < RPG; ++r) {
                const float gi = sigf(aI[r]);
                const float gf = sigf(aF[r]);
                const float gg = fmaxf(aG[r], 0.0f);
                const float cn = gf * creg[a][r] + gi * gg;
                creg[a][r] = cn;
                const float h = sigf(aO[r]) * fmaxf(cn, 0.0f);
                hnew[a][r] = h;
                if constexpr (!FUSE)
                    st1(out + ((size_t)(row0 + rloc0 + r) * TT + t) * (2 * U) + dir * U + j, h);
            }
        }

        __syncthreads();   // all reads of old h done
#pragma unroll
        for (int a = 0; a < CC; ++a)
#pragma unroll
            for (int r = 0; r < RPG; ++r)
                hbuf[rloc0 + r][a * 64 + lane] = hnew[a][r];
        __syncthreads();   // new h visible

        // ---- fused dense1 rank-U update: acc1 += h_t @ d1w[t*512+dir*256 ..]
        if constexpr (FUSE) {
            const float* wrow = d1w + ((size_t)t * 512 + dir * 256) * 256;
#pragma unroll 1
            for (int j = 0; j < 256; j += 4) {
                float w[4][4];
#pragma unroll
                for (int jj = 0; jj < 4; ++jj)
                    *(float4*)w[jj] = *(const float4*)(wrow + (size_t)(j + jj) * 256 + lane * 4);
#pragma unroll
                for (int r = 0; r < RPG; ++r) {
                    float hv[4];
                    *(float4*)hv = *(const float4*)(&hbuf[rloc0 + r][j]);
#pragma unroll
                    for (int jj = 0; jj < 4; ++jj)
#pragma unroll
                        for (int q = 0; q < 4; ++q)
                            acc1[r][q] = fmaf(hv[jj], w[jj][q], acc1[r][q]);
                }
            }
        }
    }

    if constexpr (FUSE) {
#pragma unroll
        for (int r = 0; r < RPG; ++r)
#pragma unroll
            for (int q = 0; q < 4; ++q)
                atomicAdd(&d1o[(size_t)(row0 + rloc0 + r) * 256 + lane * 4 + q], acc1[r][q]);
    }
}

// ---------------------------------------------------------------------------
__global__ __launch_bounds__(256)
void zero_f4(float* __restrict__ p)
{
    const size_t i = ((size_t)blockIdx.x * 256 + threadIdx.x) * 4;
    *(float4*)(p + i) = float4{0.0f, 0.0f, 0.0f, 0.0f};
}

// ---------------------------------------------------------------------------
// Tail: relu(d1o+d1b) -> dense2(256->128) relu -> dense3(128->64) relu ->
// batchnorm -> logits(64->26) -> softmax. One block = 16 batch rows.
// ---------------------------------------------------------------------------
__global__ __launch_bounds__(256)
void tail_kernel(const float* __restrict__ a1g, const float* __restrict__ d1b,
                 const float* __restrict__ d2w, const float* __restrict__ d2b,
                 const float* __restrict__ d3w, const float* __restrict__ d3b,
                 const float* __restrict__ bng, const float* __restrict__ bnb,
                 const float* __restrict__ bnm, const float* __restrict__ bnv,
                 const float* __restrict__ ow,  const float* __restrict__ ob,
                 float* __restrict__ outp)
{
    const int tid = threadIdx.x;
    const int row0 = blockIdx.x * 16;

    __shared__ float A1[16][256];
    __shared__ float A2[16][128];
    __shared__ float A3[16][64];
    __shared__ float LG[16][26];

    for (int i = tid; i < 16 * 256; i += 256) {
        const int c = i & 255;
        A1[i >> 8][c] = fmaxf(a1g[(size_t)row0 * 256 + i] + d1b[c], 0.0f);
    }
    __syncthreads();

    { // dense2: 16x128 outputs, 8 per thread
        const int r = tid >> 4, j0 = (tid & 15) * 8;
        float acc[8];
#pragma unroll
        for (int q = 0; q < 8; ++q) acc[q] = d2b[j0 + q];
#pragma unroll 4
        for (int k = 0; k < 256; ++k) {
            const float av = A1[r][k];
            const float* wr = d2w + (size_t)k * 128 + j0;
            float w8[8];
            *(float4*)w8       = *(const float4*)wr;
            *(float4*)(w8 + 4) = *(const float4*)(wr + 4);
#pragma unroll
            for (int q = 0; q < 8; ++q) acc[q] = fmaf(av, w8[q], acc[q]);
        }
#pragma unroll
        for (int q = 0; q < 8; ++q) A2[r][j0 + q] = fmaxf(acc[q], 0.0f);
    }
    __syncthreads();

    { // dense3 + batchnorm: 16x64 outputs, 4 per thread
        const int r = tid >> 4, j0 = (tid & 15) * 4;
        float acc[4];
#pragma unroll
        for (int q = 0; q < 4; ++q) acc[q] = d3b[j0 + q];
#pragma unroll 4
        for (int k = 0; k < 128; ++k) {
            const float av = A2[r][k];
            float w4[4];
            *(float4*)w4 = *(const float4*)(d3w + (size_t)k * 64 + j0);
#pragma unroll
            for (int q = 0; q < 4; ++q) acc[q] = fmaf(av, w4[q], acc[q]);
        }
#pragma unroll
        for (int q = 0; q < 4; ++q) {
            const int jc = j0 + q;
            const float h = fmaxf(acc[q], 0.0f);
            const float sc = bng[jc] * rsqrtf(bnv[jc] + 0.001f);
            A3[r][jc] = (h - bnm[jc]) * sc + bnb[jc];
        }
    }
    __syncthreads();

    for (int i = tid; i < 16 * 26; i += 256) { // logits (416 outputs, 256 threads)
        const int r = i / 26, jc = i % 26;
        float acc = ob[jc];
#pragma unroll 4
        for (int k = 0; k < 64; ++k) acc = fmaf(A3[r][k], ow[(size_t)k * 26 + jc], acc);
        LG[r][jc] = acc;
    }
    __syncthreads();

    if (tid < 16) { // softmax per row
        const int r = tid;
        float m = -1e30f;
        for (int c = 0; c < 26; ++c) m = fmaxf(m, LG[r][c]);
        float s = 0.0f;
        float e[26];
        for (int c = 0; c < 26; ++c) { e[c] = __expf(LG[r][c] - m); s += e[c]; }
        const float inv = 1.0f / s;
        for (int c = 0; c < 26; ++c)
            outp[(size_t)(row0 + r) * 26 + c] = e[c] * inv;
    }
}

// ---------------------------------------------------------------------------
extern "C" void kernel_launch(void* const* d_in, const int* in_sizes, int n_in,
                              void* d_out, int out_size, void* d_ws, size_t ws_size,
                              hipStream_t stream)
{
    const float* x   = (const float*)d_in[0];
    const float* w1f = (const float*)d_in[1];
    const float* u1f = (const float*)d_in[2];
    const float* b1f = (const float*)d_in[3];
    const float* w1b = (const float*)d_in[4];
    const float* u1b = (const float*)d_in[5];
    const float* b1b = (const float*)d_in[6];
    const float* w2f = (const float*)d_in[7];
    const float* u2f = (const float*)d_in[8];
    const float* b2f = (const float*)d_in[9];
    const float* w2b = (const float*)d_in[10];
    const float* u2b = (const float*)d_in[11];
    const float* b2b = (const float*)d_in[12];
    const float* w3f = (const float*)d_in[13];
    const float* u3f = (const float*)d_in[14];
    const float* b3f = (const float*)d_in[15];
    const float* w3b = (const float*)d_in[16];
    const float* u3b = (const float*)d_in[17];
    const float* b3b = (const float*)d_in[18];
    const float* d1w = (const float*)d_in[19];
    const float* d1b = (const float*)d_in[20];
    const float* d2w = (const float*)d_in[21];
    const float* d2b = (const float*)d_in[22];
    const float* d3w = (const float*)d_in[23];
    const float* d3b = (const float*)d_in[24];
    const float* bng = (const float*)d_in[25];
    const float* bnb = (const float*)d_in[26];
    const float* bnm = (const float*)d_in[27];
    const float* bnv = (const float*)d_in[28];
    const float* ow  = (const float*)d_in[29];
    const float* ob  = (const float*)d_in[30];

    const dim3 blk(256);
    const dim3 gl(BATCH / 32, 2);   // dir on y

    constexpr size_t H1 = (size_t)BATCH * TT * 128;   // 31457280 elems
    constexpr size_t H2 = (size_t)BATCH * TT * 256;   // 62914560 elems
    const size_t need_f32 = (H1 + H2) * sizeof(float); // 377,487,360 B

    if (ws_size >= need_f32) {
        // fp32 intermediates. d1o reuses h1's region (h1 dead after lstm2).
        float* h1  = (float*)d_ws;
        float* h2  = (float*)d_ws + H1;
        float* d1o = (float*)d_ws;
        lstm_k<126,  64, 32, false, float, float><<<gl, blk, 0, stream>>>(
            x,  w1f, u1f, b1f, w1b, u1b, b1b, h1, nullptr, nullptr);
        lstm_k<128, 128, 32, false, float, float><<<gl, blk, 0, stream>>>(
            h1, w2f, u2f, b2f, w2b, u2b, b2b, h2, nullptr, nullptr);
        zero_f4<<<dim3(2048), blk, 0, stream>>>(d1o);
        lstm_k<256, 256, 32, true, float, float><<<gl, blk, 0, stream>>>(
            h2, w3f, u3f, b3f, w3b, u3b, b3b, (float*)nullptr, d1w, d1o);
        tail_kernel<<<dim3(BATCH / 16), blk, 0, stream>>>(
            d1o, d1b, d2w, d2b, d3w, d3b, bng, bnb, bnm, bnv, ow, ob, (float*)d_out);
    } else {
        // fp16 intermediates (189 MB peak). d1o (fp32) reuses h1's region.
        __half* h1  = (__half*)d_ws;
        __half* h2  = (__half*)d_ws + H1;
        float*  d1o = (float*)d_ws;
        lstm_k<126,  64, 32, false, float, __half><<<gl, blk, 0, stream>>>(
            x,  w1f, u1f, b1f, w1b, u1b, b1b, h1, nullptr, nullptr);
        lstm_k<128, 128, 32, false, __half, __half><<<gl, blk, 0, stream>>>(
            h1, w2f, u2f, b2f, w2b, u2b, b2b, h2, nullptr, nullptr);
        zero_f4<<<dim3(2048), blk, 0, stream>>>(d1o);
        lstm_k<256, 256, 32, true, __half, float><<<gl, blk, 0, stream>>>(
            h2, w3f, u3f, b3f, w3b, u3b, b3b, (float*)nullptr, d1w, d1o);
        tail_kernel<<<dim3(BATCH / 16), blk, 0, stream>>>(
            d1o, d1b, d2w, d2b, d3w, d3b, bng, bnb, bnm, bnv, ow, ob, (float*)d_out);
    }
}

// Round 3
// 9401.769 us; speedup vs baseline: 1.6628x; 1.6628x over previous
//
#include <hip/hip_runtime.h>
#include <hip/hip_fp16.h>

#define TT 30
#define BATCH 8192

#ifdef __has_builtin
#if __has_builtin(__builtin_amdgcn_fdot2)
#define HAVE_FDOT2 1
#endif
#endif
#ifndef HAVE_FDOT2
#define HAVE_FDOT2 0
#endif

typedef _Float16 f16x2 __attribute__((ext_vector_type(2)));

__device__ __forceinline__ float sigf(float x) { return 1.0f / (1.0f + __expf(-x)); }

__device__ __forceinline__ float fdot2f(unsigned a, unsigned b, float c) {
#if HAVE_FDOT2
    return __builtin_amdgcn_fdot2(__builtin_bit_cast(f16x2, a),
                                  __builtin_bit_cast(f16x2, b), c, false);
#else
    const f16x2 av = __builtin_bit_cast(f16x2, a), bv = __builtin_bit_cast(f16x2, b);
    return c + (float)av.x * (float)bv.x + (float)av.y * (float)bv.y;
#endif
}
__device__ __forceinline__ float dot8(const uint4 a, const uint4 b, float c) {
    c = fdot2f(a.x, b.x, c);
    c = fdot2f(a.y, b.y, c);
    c = fdot2f(a.z, b.z, c);
    c = fdot2f(a.w, b.w, c);
    return c;
}

// ---------------------------------------------------------------------------
// Weight packing: src fp32 (K x 4U), gate-major cols [i|f|g|o] each U wide
//   -> dst f16 P[k8][j in U][gate 4][kq 8]  (16B per (k8,j,gate) -> uint4 load)
// ---------------------------------------------------------------------------
template<int UCOLS>
__global__ __launch_bounds__(256)
void pack_lstm(const float* __restrict__ src, __half* __restrict__ dst)
{
    const int i  = blockIdx.x * 256 + threadIdx.x;
    const int kq = i & 7;
    const int g  = (i >> 3) & 3;
    const int j  = (i >> 5) & (UCOLS - 1);
    const int k8 = i / (UCOLS * 32);
    const int k  = k8 * 8 + kq;
    dst[i] = __float2half(src[(size_t)k * (4 * UCOLS) + g * UCOLS + j]);
}

// d1w (15360,256) fp32 -> f16 slabs [t*2+dir][k8 32][n 256][kq 8]
__global__ __launch_bounds__(256)
void pack_d1w(const float* __restrict__ src, __half* __restrict__ dst)
{
    const int i    = blockIdx.x * 256 + threadIdx.x;   // < 3,932,160
    const int kq   = i & 7;
    const int n    = (i >> 3) & 255;
    const int k8   = (i >> 11) & 31;
    const int slab = i >> 16;                          // t*2 + dir
    const int t = slab >> 1, d = slab & 1;
    const int k = k8 * 8 + kq;
    dst[i] = __float2half(src[(size_t)(t * 512 + d * 256 + k) * 256 + n]);
}

// ---------------------------------------------------------------------------
// Fused bidirectional LSTM layer, f16 dot2 math, fp32 accumulate/state.
// Block = RB batch rows x one direction, iterates all TT steps; h (f16) in
// LDS; c (fp32) in regs. Wave = RPG rows, covers all columns; ALIVE column
// chunks (64 cols x 4 gates each) processed simultaneously to amortize x/h
// fragment loads. Gate order i,f,g,o; c=sig(f)c+sig(i)relu(g); h=sig(o)relu(c).
// FUSE (lstm3): per-step rank-256 dense1 update instead of writing h3.
// ---------------------------------------------------------------------------
template<int DIN, int U, int RB, int ALIVE, bool FUSE, bool F32IN>
__global__ __launch_bounds__(256, 2)
void lstm_k(const void* __restrict__ xin,
            const float* __restrict__ w32f, const float* __restrict__ w32b,   // layer1 input W (fp32, unpacked)
            const __half* __restrict__ wpf, const __half* __restrict__ wpb,   // packed input W
            const __half* __restrict__ upf, const __half* __restrict__ upb,   // packed recurrent U
            const float* __restrict__ biasf, const float* __restrict__ biasb,
            __half* __restrict__ out,
            const __half* __restrict__ d1wp, float* __restrict__ d1o)
{
    constexpr int CC  = U / 64;
    constexpr int RPG = RB / 4;
    constexpr int NP  = CC / ALIVE;
    constexpr int K8R = U / 8;
    static_assert(CC % ALIVE == 0, "");
    static_assert(!FUSE || (U == 256 && RB == 32), "");
    static_assert(!F32IN || (CC == 1 && ALIVE == 1), "");

    const int dir = blockIdx.y;
    const float*  __restrict__ bias = dir ? biasb : biasf;
    const __half* __restrict__ Wp   = dir ? wpb : wpf;
    const __half* __restrict__ Up   = dir ? upb : upf;
    const float*  __restrict__ W32  = dir ? w32b : w32f;

    const int lane  = threadIdx.x & 63;
    const int wv    = threadIdx.x >> 6;
    const int rloc0 = wv * RPG;
    const int row0  = blockIdx.x * RB;

    __shared__ __align__(16) __half hbuf[RB][U];

    float creg[CC][RPG];
#pragma unroll
    for (int a = 0; a < CC; ++a)
#pragma unroll
        for (int r = 0; r < RPG; ++r) creg[a][r] = 0.0f;

    float acc1[FUSE ? RPG : 1][4];
#pragma unroll
    for (int r = 0; r < (FUSE ? RPG : 1); ++r)
#pragma unroll
        for (int q = 0; q < 4; ++q) acc1[r][q] = 0.0f;

    for (int i = threadIdx.x; i < RB * U; i += 256)
        (&hbuf[0][0])[i] = __float2half(0.0f);

    float bg[CC][4];
#pragma unroll
    for (int a = 0; a < CC; ++a)
#pragma unroll
        for (int g = 0; g < 4; ++g) bg[a][g] = bias[g * U + a * 64 + lane];

    __syncthreads();

#pragma unroll 1
    for (int s = 0; s < TT; ++s) {
        const int t = dir ? (TT - 1 - s) : s;
        float hnew[CC][RPG];

#pragma unroll
        for (int p = 0; p < NP; ++p) {
            float ac[ALIVE][4][RPG];
#pragma unroll
            for (int ai = 0; ai < ALIVE; ++ai)
#pragma unroll
                for (int g = 0; g < 4; ++g)
#pragma unroll
                    for (int r = 0; r < RPG; ++r) ac[ai][g][r] = bg[p * ALIVE + ai][g];

            // ---- input contribution ----
            if constexpr (F32IN) {
                const float* xf = (const float*)xin;
#pragma unroll 2
                for (int k = 0; k < DIN; k += 2) {
                    float w0[4], w1[4];
#pragma unroll
                    for (int g = 0; g < 4; ++g) {
                        w0[g] = W32[(size_t)(k    ) * (4 * U) + g * U + lane];
                        w1[g] = W32[(size_t)(k + 1) * (4 * U) + g * U + lane];
                    }
#pragma unroll
                    for (int r = 0; r < RPG; ++r) {
                        const float2 xv = *(const float2*)(xf + ((size_t)(row0 + rloc0 + r) * TT + t) * DIN + k);
#pragma unroll
                        for (int g = 0; g < 4; ++g) {
                            ac[0][g][r] = fmaf(xv.x, w0[g], ac[0][g][r]);
                            ac[0][g][r] = fmaf(xv.y, w1[g], ac[0][g][r]);
                        }
                    }
                }
            } else {
                const __half* xh = (const __half*)xin;
                constexpr int K8IN = DIN / 8;
#pragma unroll 1
                for (int k8 = 0; k8 < K8IN; ++k8) {
                    uint4 w[ALIVE][4];
#pragma unroll
                    for (int ai = 0; ai < ALIVE; ++ai)
#pragma unroll
                        for (int g = 0; g < 4; ++g)
                            w[ai][g] = *(const uint4*)(Wp + (((size_t)k8 * U + (p * ALIVE + ai) * 64 + lane) * 4 + g) * 8);
#pragma unroll
                    for (int r = 0; r < RPG; ++r) {
                        const uint4 xq = *(const uint4*)(xh + ((size_t)(row0 + rloc0 + r) * TT + t) * DIN + k8 * 8);
#pragma unroll
                        for (int ai = 0; ai < ALIVE; ++ai)
#pragma unroll
                            for (int g = 0; g < 4; ++g)
                                ac[ai][g][r] = dot8(xq, w[ai][g], ac[ai][g][r]);
                    }
                }
            }

            // ---- recurrent contribution ----
#pragma unroll 1
            for (int k8 = 0; k8 < K8R; ++k8) {
                uint4 w[ALIVE][4];
#pragma unroll
                for (int ai = 0; ai < ALIVE; ++ai)
#pragma unroll
                    for (int g = 0; g < 4; ++g)
                        w[ai][g] = *(const uint4*)(Up + (((size_t)k8 * U + (p * ALIVE + ai) * 64 + lane) * 4 + g) * 8);
#pragma unroll
                for (int r = 0; r < RPG; ++r) {
                    const uint4 hq = *(const uint4*)(&hbuf[rloc0 + r][k8 * 8]);
#pragma unroll
                    for (int ai = 0; ai < ALIVE; ++ai)
#pragma unroll
                        for (int g = 0; g < 4; ++g)
                            ac[ai][g][r] = dot8(hq, w[ai][g], ac[ai][g][r]);
                }
            }

            // ---- gates / state ----
#pragma unroll
            for (int ai = 0; ai < ALIVE; ++ai) {
                const int a = p * ALIVE + ai;
#pragma unroll
                for (int r = 0; r < RPG; ++r) {
                    const float gi = sigf(ac[ai][0][r]);
                    const float gf = sigf(ac[ai][1][r]);
                    const float gg = fmaxf(ac[ai][2][r], 0.0f);
                    const float cn = gf * creg[a][r] + gi * gg;
                    creg[a][r] = cn;
                    const float h = sigf(ac[ai][3][r]) * fmaxf(cn, 0.0f);
                    hnew[a][r] = h;
                    if constexpr (!FUSE)
                        out[((size_t)(row0 + rloc0 + r) * TT + t) * (2 * U) + dir * U + a * 64 + lane] = __float2half(h);
                }
            }
        }

        __syncthreads();   // all reads of old h done
#pragma unroll
        for (int a = 0; a < CC; ++a)
#pragma unroll
            for (int r = 0; r < RPG; ++r)
                hbuf[rloc0 + r][a * 64 + lane] = __float2half(hnew[a][r]);
        __syncthreads();   // new h visible

        // ---- fused dense1 rank-256 update ----
        if constexpr (FUSE) {
            const __half* slab = d1wp + (size_t)(t * 2 + dir) * 65536;
#pragma unroll 2
            for (int k8 = 0; k8 < 32; ++k8) {
                uint4 wq[4];
#pragma unroll
                for (int q = 0; q < 4; ++q)
                    wq[q] = *(const uint4*)(slab + ((size_t)k8 * 256 + lane * 4 + q) * 8);
#pragma unroll
                for (int r = 0; r < RPG; ++r) {
                    const uint4 hq = *(const uint4*)(&hbuf[rloc0 + r][k8 * 8]);
#pragma unroll
                    for (int q = 0; q < 4; ++q)
                        acc1[r][q] = dot8(hq, wq[q], acc1[r][q]);
                }
            }
        }
    }

    if constexpr (FUSE) {
#pragma unroll
        for (int r = 0; r < RPG; ++r)
#pragma unroll
            for (int q = 0; q < 4; ++q)
                atomicAdd(&d1o[(size_t)(row0 + rloc0 + r) * 256 + lane * 4 + q], acc1[r][q]);
    }
}

// ---------------------------------------------------------------------------
__global__ __launch_bounds__(256)
void zero_f4(float* __restrict__ p)
{
    const size_t i = ((size_t)blockIdx.x * 256 + threadIdx.x) * 4;
    *(float4*)(p + i) = float4{0.0f, 0.0f, 0.0f, 0.0f};
}

// ---------------------------------------------------------------------------
// Tail: relu(d1o+d1b) -> dense2(256->128) relu -> dense3(128->64) relu ->
// batchnorm -> logits(64->26) -> softmax. One block = 16 batch rows.
// ---------------------------------------------------------------------------
__global__ __launch_bounds__(256)
void tail_kernel(const float* __restrict__ a1g, const float* __restrict__ d1b,
                 const float* __restrict__ d2w, const float* __restrict__ d2b,
                 const float* __restrict__ d3w, const float* __restrict__ d3b,
                 const float* __restrict__ bng, const float* __restrict__ bnb,
                 const float* __restrict__ bnm, const float* __restrict__ bnv,
                 const float* __restrict__ ow,  const float* __restrict__ ob,
                 float* __restrict__ outp)
{
    const int tid = threadIdx.x;
    const int row0 = blockIdx.x * 16;

    __shared__ float A1[16][256];
    __shared__ float A2[16][128];
    __shared__ float A3[16][64];
    __shared__ float LG[16][26];

    for (int i = tid; i < 16 * 256; i += 256) {
        const int c = i & 255;
        A1[i >> 8][c] = fmaxf(a1g[(size_t)row0 * 256 + i] + d1b[c], 0.0f);
    }
    __syncthreads();

    { // dense2: 16x128 outputs, 8 per thread
        const int r = tid >> 4, j0 = (tid & 15) * 8;
        float acc[8];
#pragma unroll
        for (int q = 0; q < 8; ++q) acc[q] = d2b[j0 + q];
#pragma unroll 4
        for (int k = 0; k < 256; ++k) {
            const float av = A1[r][k];
            const float* wr = d2w + (size_t)k * 128 + j0;
            float w8[8];
            *(float4*)w8       = *(const float4*)wr;
            *(float4*)(w8 + 4) = *(const float4*)(wr + 4);
#pragma unroll
            for (int q = 0; q < 8; ++q) acc[q] = fmaf(av, w8[q], acc[q]);
        }
#pragma unroll
        for (int q = 0; q < 8; ++q) A2[r][j0 + q] = fmaxf(acc[q], 0.0f);
    }
    __syncthreads();

    { // dense3 + batchnorm
        const int r = tid >> 4, j0 = (tid & 15) * 4;
        float acc[4];
#pragma unroll
        for (int q = 0; q < 4; ++q) acc[q] = d3b[j0 + q];
#pragma unroll 4
        for (int k = 0; k < 128; ++k) {
            const float av = A2[r][k];
            float w4[4];
            *(float4*)w4 = *(const float4*)(d3w + (size_t)k * 64 + j0);
#pragma unroll
            for (int q = 0; q < 4; ++q) acc[q] = fmaf(av, w4[q], acc[q]);
        }
#pragma unroll
        for (int q = 0; q < 4; ++q) {
            const int jc = j0 + q;
            const float h = fmaxf(acc[q], 0.0f);
            const float sc = bng[jc] * rsqrtf(bnv[jc] + 0.001f);
            A3[r][jc] = (h - bnm[jc]) * sc + bnb[jc];
        }
    }
    __syncthreads();

    for (int i = tid; i < 16 * 26; i += 256) { // logits
        const int r = i / 26, jc = i % 26;
        float acc = ob[jc];
#pragma unroll 4
        for (int k = 0; k < 64; ++k) acc = fmaf(A3[r][k], ow[(size_t)k * 26 + jc], acc);
        LG[r][jc] = acc;
    }
    __syncthreads();

    if (tid < 16) { // softmax
        const int r = tid;
        float m = -1e30f;
        for (int c = 0; c < 26; ++c) m = fmaxf(m, LG[r][c]);
        float s = 0.0f;
        float e[26];
        for (int c = 0; c < 26; ++c) { e[c] = __expf(LG[r][c] - m); s += e[c]; }
        const float inv = 1.0f / s;
        for (int c = 0; c < 26; ++c)
            outp[(size_t)(row0 + r) * 26 + c] = e[c] * inv;
    }
}

// ---------------------------------------------------------------------------
extern "C" void kernel_launch(void* const* d_in, const int* in_sizes, int n_in,
                              void* d_out, int out_size, void* d_ws, size_t ws_size,
                              hipStream_t stream)
{
    const float* x   = (const float*)d_in[0];
    const float* w1f = (const float*)d_in[1];
    const float* u1f = (const float*)d_in[2];
    const float* b1f = (const float*)d_in[3];
    const float* w1b = (const float*)d_in[4];
    const float* u1b = (const float*)d_in[5];
    const float* b1b = (const float*)d_in[6];
    const float* w2f = (const float*)d_in[7];
    const float* u2f = (const float*)d_in[8];
    const float* b2f = (const float*)d_in[9];
    const float* w2b = (const float*)d_in[10];
    const float* u2b = (const float*)d_in[11];
    const float* b2b = (const float*)d_in[12];
    const float* w3f = (const float*)d_in[13];
    const float* u3f = (const float*)d_in[14];
    const float* b3f = (const float*)d_in[15];
    const float* w3b = (const float*)d_in[16];
    const float* u3b = (const float*)d_in[17];
    const float* b3b = (const float*)d_in[18];
    const float* d1w = (const float*)d_in[19];
    const float* d1b = (const float*)d_in[20];
    const float* d2w = (const float*)d_in[21];
    const float* d2b = (const float*)d_in[22];
    const float* d3w = (const float*)d_in[23];
    const float* d3b = (const float*)d_in[24];
    const float* bng = (const float*)d_in[25];
    const float* bnb = (const float*)d_in[26];
    const float* bnm = (const float*)d_in[27];
    const float* bnv = (const float*)d_in[28];
    const float* ow  = (const float*)d_in[29];
    const float* ob  = (const float*)d_in[30];

    // Workspace map (bytes). Known: ws_size >= 188,743,680 (R2 fp16 path ran).
    //   [0 .. 62,914,560)            h1 f16 (B,T,128)  -- dead after lstm2:
    //        @0          d1o fp32 (8,388,608 B)
    //        @8,388,608  d1wp f16 (7,864,320 B)
    //        @16,252,928 w3f/u3f/w3b/u3b packs f16 (4 x 524,288 B)
    //   [62,914,560 .. 188,743,680)  h2 f16 (B,T,256)
    //   [188,743,680 .. 189,333,504) u1/w2/u2 packs f16 (589,824 B)
    char* wsb = (char*)d_ws;
    __half* h1 = (__half*)wsb;
    __half* h2 = (__half*)(wsb + 62914560);
    __half* sp = (__half*)(wsb + 188743680);
    __half* pu1f = sp;           __half* pu1b = sp + 16384;
    __half* pw2f = sp + 32768;   __half* pu2f = sp + 98304;
    __half* pw2b = sp + 163840;  __half* pu2b = sp + 229376;
    float*  d1o  = (float*)wsb;
    __half* d1wp = (__half*)(wsb + 8388608);
    __half* pw3f = (__half*)(wsb + 16252928);
    __half* pu3f = (__half*)(wsb + 16777216);
    __half* pw3b = (__half*)(wsb + 17301504);
    __half* pu3b = (__half*)(wsb + 17825792);

    const dim3 blk(256);
    const dim3 gl(BATCH / 32, 2);   // dir on y

    // packs needed before lstm1/lstm2
    pack_lstm< 64><<<dim3(  64), blk, 0, stream>>>(u1f, pu1f);
    pack_lstm< 64><<<dim3(  64), blk, 0, stream>>>(u1b, pu1b);
    pack_lstm<128><<<dim3( 256), blk, 0, stream>>>(w2f, pw2f);
    pack_lstm<128><<<dim3( 256), blk, 0, stream>>>(u2f, pu2f);
    pack_lstm<128><<<dim3( 256), blk, 0, stream>>>(w2b, pw2b);
    pack_lstm<128><<<dim3( 256), blk, 0, stream>>>(u2b, pu2b);

    lstm_k<126,  64, 32, 1, false, true ><<<gl, blk, 0, stream>>>(
        x, w1f, w1b, nullptr, nullptr, pu1f, pu1b, b1f, b1b, h1, nullptr, nullptr);
    lstm_k<128, 128, 32, 2, false, false><<<gl, blk, 0, stream>>>(
        h1, nullptr, nullptr, pw2f, pw2b, pu2f, pu2b, b2f, b2b, h2, nullptr, nullptr);

    // h1 dead: carve d1o, d1wp, layer-3 packs out of its region
    zero_f4<<<dim3(2048), blk, 0, stream>>>(d1o);
    pack_d1w<<<dim3(15360), blk, 0, stream>>>(d1w, d1wp);
    pack_lstm<256><<<dim3(1024), blk, 0, stream>>>(w3f, pw3f);
    pack_lstm<256><<<dim3(1024), blk, 0, stream>>>(u3f, pu3f);
    pack_lstm<256><<<dim3(1024), blk, 0, stream>>>(w3b, pw3b);
    pack_lstm<256><<<dim3(1024), blk, 0, stream>>>(u3b, pu3b);

    lstm_k<256, 256, 32, 2, true, false><<<gl, blk, 0, stream>>>(
        h2, nullptr, nullptr, pw3f, pw3b, pu3f, pu3b, b3f, b3b, nullptr, d1wp, d1o);

    tail_kernel<<<dim3(BATCH / 16), blk, 0, stream>>>(
        d1o, d1b, d2w, d2b, d3w, d3b, bng, bnb, bnm, bnv, ow, ob, (float*)d_out);
}

// Round 4
// 2883.686 us; speedup vs baseline: 5.4212x; 3.2603x over previous
//
#include <hip/hip_runtime.h>
#include <hip/hip_fp16.h>

#define TT 30
#define BATCH 8192

typedef _Float16 f16x8v __attribute__((ext_vector_type(8)));
typedef float    f32x4v __attribute__((ext_vector_type(4)));
typedef unsigned int u32x4v __attribute__((ext_vector_type(4)));

__device__ __forceinline__ float sigf(float x) { return 1.0f / (1.0f + __expf(-x)); }

__device__ __forceinline__ f16x8v ldb16(const __half* p) {
    return __builtin_bit_cast(f16x8v, *(const u32x4v*)p);
}
__device__ __forceinline__ f32x4v mfma16(f16x8v a, f16x8v b, f32x4v c) {
    return __builtin_amdgcn_mfma_f32_16x16x32_f16(a, b, c, 0, 0, 0);
}

// ---------------------------------------------------------------------------
// x (B,T,126) fp32 -> x16 (B,T,128) f16, zero-padded cols 126..127
// ---------------------------------------------------------------------------
__global__ __launch_bounds__(256)
void x_to_f16(const float* __restrict__ x, __half* __restrict__ x16)
{
    const size_t i = (size_t)blockIdx.x * 256 + threadIdx.x;  // < B*T*128
    const int k = (int)(i & 127);
    const size_t bt = i >> 7;
    x16[i] = (k < 126) ? __float2half(x[bt * 126 + k]) : __half(0.0f);
}

// ---------------------------------------------------------------------------
// Pack LSTM weights into MFMA B-fragment order.
// Source: W (DINS x 4U), Urec (U x 4U), gate-major cols [i|f|g|o].
// Dest flat: [dir][wave 4][nt NT][kt KT][lane 64][jj 8], where the fragment
// element is B[k = kt*32 + (lane>>4)*8 + jj][col = g*U + w*(U/4) + jhi*16 +
// (lane&15)] with g = nt/JH, jhi = nt%JH. K rows: [W rows 0..DINP) (>=DINS
// zero-padded), then Urec rows.
// ---------------------------------------------------------------------------
template<int DINS, int DINP, int U>
__global__ __launch_bounds__(256)
void pack_b(const float* __restrict__ wf, const float* __restrict__ uf,
            const float* __restrict__ wb, const float* __restrict__ ub,
            __half* __restrict__ dst)
{
    constexpr int NT = U / 16, KT = (DINP + U) / 32, JH = U / 64;
    const int i = blockIdx.x * 256 + threadIdx.x;   // < 4096*NT*KT
    const int jj   = i & 7;
    const int lane = (i >> 3) & 63;
    const int kt   = (i >> 9) % KT;
    const int nt   = ((i >> 9) / KT) % NT;
    const int w    = ((i >> 9) / KT / NT) % 4;
    const int d    = (i >> 9) / KT / NT / 4;
    const int g = nt / JH, jhi = nt % JH;
    const int col = g * U + w * (U / 4) + jhi * 16 + (lane & 15);
    const int k = kt * 32 + (lane >> 4) * 8 + jj;
    const float* __restrict__ W  = d ? wb : wf;
    const float* __restrict__ Ur = d ? ub : uf;
    float v;
    if (k < DINS)      v = W[(size_t)k * (4 * U) + col];
    else if (k < DINP) v = 0.0f;
    else               v = Ur[(size_t)(k - DINP) * (4 * U) + col];
    dst[i] = __float2half(v);
}

// ---------------------------------------------------------------------------
// Pack d1w (15360,256) into per-(t,dir) B-fragment slabs:
// [t 30][d 2][wave 4][nt 4][kt 8][lane 64][jj 8];
// element = d1w[(t*512 + d*256 + k)*256 + n], k = kt*32+(lane>>4)*8+jj,
// n = w*64 + nt*16 + (lane&15).
// ---------------------------------------------------------------------------
__global__ __launch_bounds__(256)
void pack_d1(const float* __restrict__ src, __half* __restrict__ dst)
{
    const int i = blockIdx.x * 256 + threadIdx.x;   // < 3,932,160
    const int jj   = i & 7;
    const int lane = (i >> 3) & 63;
    const int kt   = (i >> 9) & 7;
    const int nt   = (i >> 12) & 3;
    const int w    = (i >> 14) & 3;
    const int d    = (i >> 16) & 1;
    const int t    = i >> 17;
    const int n = w * 64 + nt * 16 + (lane & 15);
    const int k = kt * 32 + (lane >> 4) * 8 + jj;
    dst[i] = __float2half(src[(size_t)(t * 512 + d * 256 + k) * 256 + n]);
}

// ---------------------------------------------------------------------------
// MFMA bidirectional LSTM layer. Block = 32 batch rows x one direction,
// 256 threads (4 waves), iterates all TT steps.
// Per step: Z[32][4U] = [x_t | h] @ [W;U] + b via 16x16x32 f16 MFMA.
// Wave w owns N-columns {g*U + w*(U/4) + jhi*16 + c} (all 4 gates of its
// (U/4)-col hidden slice -> gates align per-thread in C-layout).
// h (f16) in LDS (row stride U+8: 16B-aligned, 2-lane/bank = free).
// c (fp32) in VGPRs at C-layout (row=quad*4+reg, col=lane&15).
// FUSE (lstm3): per-step rank-256 dense1 MFMA update, atomicAdd epilogue.
// ---------------------------------------------------------------------------
template<int DIN, int U, bool FUSE>
__global__ __launch_bounds__(256, 2)
void lstm_mfma(const __half* __restrict__ xin,    // (B,T,DIN) f16
               const __half* __restrict__ PB,     // packed weights
               const float* __restrict__ biasf, const float* __restrict__ biasb,
               __half* __restrict__ out,          // (B,T,2U) f16 (non-FUSE)
               const __half* __restrict__ PD1, float* __restrict__ d1o)
{
    constexpr int NT = U / 16, KT = (DIN + U) / 32, KTI = DIN / 32;
    constexpr int JH = U / 64, HS = U + 8;
    const int dir = blockIdx.y;
    const int tid = threadIdx.x;
    const int lane = tid & 63, wv = tid >> 6;
    const int l16 = lane & 15, quad = lane >> 4;
    const int row0 = blockIdx.x * 32;
    const float* __restrict__ bias = dir ? biasb : biasf;

    __shared__ __align__(16) __half hbuf[32][HS];

    float bg[NT];
#pragma unroll
    for (int nt = 0; nt < NT; ++nt) {
        const int g = nt / JH, jhi = nt % JH;
        bg[nt] = bias[g * U + wv * (U / 4) + jhi * 16 + l16];
    }

    float creg[2][JH][4];
#pragma unroll
    for (int mt = 0; mt < 2; ++mt)
#pragma unroll
        for (int jhi = 0; jhi < JH; ++jhi)
#pragma unroll
            for (int r = 0; r < 4; ++r) creg[mt][jhi][r] = 0.0f;

    f32x4v acc1[FUSE ? 2 : 1][FUSE ? 4 : 1];
#pragma unroll
    for (int mt = 0; mt < (FUSE ? 2 : 1); ++mt)
#pragma unroll
        for (int nt = 0; nt < (FUSE ? 4 : 1); ++nt)
            acc1[mt][nt] = f32x4v{0.0f, 0.0f, 0.0f, 0.0f};

    for (int i = tid; i < 32 * HS; i += 256) ((__half*)hbuf)[i] = __half(0.0f);
    __syncthreads();

    const __half* __restrict__ PBw = PB + (size_t)(dir * 4 + wv) * (NT * KT * 512);
    const size_t xb0 = (size_t)(row0 + l16) * TT * DIN;
    const size_t xb1 = xb0 + (size_t)16 * TT * DIN;

#pragma unroll 1
    for (int s = 0; s < TT; ++s) {
        const int t = dir ? (TT - 1 - s) : s;

        f32x4v acc[2][NT];
#pragma unroll
        for (int mt = 0; mt < 2; ++mt)
#pragma unroll
            for (int nt = 0; nt < NT; ++nt)
                acc[mt][nt] = f32x4v{bg[nt], bg[nt], bg[nt], bg[nt]};

        const __half* xr0 = xin + xb0 + (size_t)t * DIN + quad * 8;
        const __half* xr1 = xin + xb1 + (size_t)t * DIN + quad * 8;

        // ---- input contribution (K-tiles 0..KTI) ----
#pragma unroll 2
        for (int kt = 0; kt < KTI; ++kt) {
            const f16x8v a0 = ldb16(xr0 + kt * 32);
            const f16x8v a1 = ldb16(xr1 + kt * 32);
            const __half* bp = PBw + (size_t)kt * 512 + lane * 8;
#pragma unroll
            for (int nt = 0; nt < NT; ++nt) {
                const f16x8v b = ldb16(bp + (size_t)nt * KT * 512);
                acc[0][nt] = mfma16(a0, b, acc[0][nt]);
                acc[1][nt] = mfma16(a1, b, acc[1][nt]);
            }
        }
        // ---- recurrent contribution (K-tiles KTI..KT) ----
#pragma unroll 2
        for (int kt = KTI; kt < KT; ++kt) {
            const f16x8v a0 = ldb16(&hbuf[l16][(kt - KTI) * 32 + quad * 8]);
            const f16x8v a1 = ldb16(&hbuf[16 + l16][(kt - KTI) * 32 + quad * 8]);
            const __half* bp = PBw + (size_t)kt * 512 + lane * 8;
#pragma unroll
            for (int nt = 0; nt < NT; ++nt) {
                const f16x8v b = ldb16(bp + (size_t)nt * KT * 512);
                acc[0][nt] = mfma16(a0, b, acc[0][nt]);
                acc[1][nt] = mfma16(a1, b, acc[1][nt]);
            }
        }

        // ---- gates / state (C-layout: row=quad*4+r, col=l16) ----
        float hv[2][JH][4];
#pragma unroll
        for (int mt = 0; mt < 2; ++mt)
#pragma unroll
            for (int jhi = 0; jhi < JH; ++jhi)
#pragma unroll
                for (int r = 0; r < 4; ++r) {
                    const float zi = acc[mt][0 * JH + jhi][r];
                    const float zf = acc[mt][1 * JH + jhi][r];
                    const float zg = acc[mt][2 * JH + jhi][r];
                    const float zo = acc[mt][3 * JH + jhi][r];
                    const float cn = sigf(zf) * creg[mt][jhi][r] + sigf(zi) * fmaxf(zg, 0.0f);
                    creg[mt][jhi][r] = cn;
                    hv[mt][jhi][r] = sigf(zo) * fmaxf(cn, 0.0f);
                }

        __syncthreads();   // all reads of h(s-1) complete
#pragma unroll
        for (int mt = 0; mt < 2; ++mt)
#pragma unroll
            for (int jhi = 0; jhi < JH; ++jhi)
#pragma unroll
                for (int r = 0; r < 4; ++r)
                    hbuf[mt * 16 + quad * 4 + r][wv * (U / 4) + jhi * 16 + l16] =
                        __float2half(hv[mt][jhi][r]);
        __syncthreads();   // h(s) visible

        if constexpr (FUSE) {
            // dense1 rank-256 update: acc1 += h_t @ d1w_slab(t,dir)
            const __half* slab = PD1 + (size_t)((t * 2 + dir) * 4 + wv) * (4 * 8 * 512) + lane * 8;
#pragma unroll 2
            for (int kt = 0; kt < 8; ++kt) {
                const f16x8v a0 = ldb16(&hbuf[l16][kt * 32 + quad * 8]);
                const f16x8v a1 = ldb16(&hbuf[16 + l16][kt * 32 + quad * 8]);
#pragma unroll
                for (int nt = 0; nt < 4; ++nt) {
                    const f16x8v b = ldb16(slab + (size_t)(nt * 8 + kt) * 512);
                    acc1[0][nt] = mfma16(a0, b, acc1[0][nt]);
                    acc1[1][nt] = mfma16(a1, b, acc1[1][nt]);
                }
            }
        } else {
            // coalesced h-out: (B,T,2U), this block's 32 rows, dir half
            constexpr int CH = U / 8;   // 16B chunks per row
            for (int i = tid; i < 32 * CH; i += 256) {
                const int r = i / CH, cc = (i % CH) * 8;
                *(u32x4v*)(out + ((size_t)(row0 + r) * TT + t) * (2 * U) + dir * U + cc) =
                    *(const u32x4v*)&hbuf[r][cc];
            }
        }
    }

    if constexpr (FUSE) {
#pragma unroll
        for (int mt = 0; mt < 2; ++mt)
#pragma unroll
            for (int nt = 0; nt < 4; ++nt)
#pragma unroll
                for (int r = 0; r < 4; ++r)
                    atomicAdd(d1o + (size_t)(row0 + mt * 16 + quad * 4 + r) * 256 +
                                  wv * 64 + nt * 16 + l16,
                              acc1[mt][nt][r]);
    }
}

// ---------------------------------------------------------------------------
__global__ __launch_bounds__(256)
void zero_f4(float* __restrict__ p)
{
    const size_t i = ((size_t)blockIdx.x * 256 + threadIdx.x) * 4;
    *(float4*)(p + i) = float4{0.0f, 0.0f, 0.0f, 0.0f};
}

// ---------------------------------------------------------------------------
// Tail: relu(d1o+d1b) -> dense2(256->128) relu -> dense3(128->64) relu ->
// batchnorm -> logits(64->26) -> softmax. One block = 16 batch rows.
// ---------------------------------------------------------------------------
__global__ __launch_bounds__(256)
void tail_kernel(const float* __restrict__ a1g, const float* __restrict__ d1b,
                 const float* __restrict__ d2w, const float* __restrict__ d2b,
                 const float* __restrict__ d3w, const float* __restrict__ d3b,
                 const float* __restrict__ bng, const float* __restrict__ bnb,
                 const float* __restrict__ bnm, const float* __restrict__ bnv,
                 const float* __restrict__ ow,  const float* __restrict__ ob,
                 float* __restrict__ outp)
{
    const int tid = threadIdx.x;
    const int row0 = blockIdx.x * 16;

    __shared__ float A1[16][256];
    __shared__ float A2[16][128];
    __shared__ float A3[16][64];
    __shared__ float LG[16][26];

    for (int i = tid; i < 16 * 256; i += 256) {
        const int c = i & 255;
        A1[i >> 8][c] = fmaxf(a1g[(size_t)row0 * 256 + i] + d1b[c], 0.0f);
    }
    __syncthreads();

    { // dense2: 16x128 outputs, 8 per thread
        const int r = tid >> 4, j0 = (tid & 15) * 8;
        float acc[8];
#pragma unroll
        for (int q = 0; q < 8; ++q) acc[q] = d2b[j0 + q];
#pragma unroll 4
        for (int k = 0; k < 256; ++k) {
            const float av = A1[r][k];
            const float* wr = d2w + (size_t)k * 128 + j0;
            float w8[8];
            *(float4*)w8       = *(const float4*)wr;
            *(float4*)(w8 + 4) = *(const float4*)(wr + 4);
#pragma unroll
            for (int q = 0; q < 8; ++q) acc[q] = fmaf(av, w8[q], acc[q]);
        }
#pragma unroll
        for (int q = 0; q < 8; ++q) A2[r][j0 + q] = fmaxf(acc[q], 0.0f);
    }
    __syncthreads();

    { // dense3 + batchnorm
        const int r = tid >> 4, j0 = (tid & 15) * 4;
        float acc[4];
#pragma unroll
        for (int q = 0; q < 4; ++q) acc[q] = d3b[j0 + q];
#pragma unroll 4
        for (int k = 0; k < 128; ++k) {
            const float av = A2[r][k];
            float w4[4];
            *(float4*)w4 = *(const float4*)(d3w + (size_t)k * 64 + j0);
#pragma unroll
            for (int q = 0; q < 4; ++q) acc[q] = fmaf(av, w4[q], acc[q]);
        }
#pragma unroll
        for (int q = 0; q < 4; ++q) {
            const int jc = j0 + q;
            const float h = fmaxf(acc[q], 0.0f);
            const float sc = bng[jc] * rsqrtf(bnv[jc] + 0.001f);
            A3[r][jc] = (h - bnm[jc]) * sc + bnb[jc];
        }
    }
    __syncthreads();

    for (int i = tid; i < 16 * 26; i += 256) { // logits
        const int r = i / 26, jc = i % 26;
        float acc = ob[jc];
#pragma unroll 4
        for (int k = 0; k < 64; ++k) acc = fmaf(A3[r][k], ow[(size_t)k * 26 + jc], acc);
        LG[r][jc] = acc;
    }
    __syncthreads();

    if (tid < 16) { // softmax
        const int r = tid;
        float m = -1e30f;
        for (int c = 0; c < 26; ++c) m = fmaxf(m, LG[r][c]);
        float s = 0.0f;
        float e[26];
        for (int c = 0; c < 26; ++c) { e[c] = __expf(LG[r][c] - m); s += e[c]; }
        const float inv = 1.0f / s;
        for (int c = 0; c < 26; ++c)
            outp[(size_t)(row0 + r) * 26 + c] = e[c] * inv;
    }
}

// ---------------------------------------------------------------------------
extern "C" void kernel_launch(void* const* d_in, const int* in_sizes, int n_in,
                              void* d_out, int out_size, void* d_ws, size_t ws_size,
                              hipStream_t stream)
{
    const float* x   = (const float*)d_in[0];
    const float* w1f = (const float*)d_in[1];
    const float* u1f = (const float*)d_in[2];
    const float* b1f = (const float*)d_in[3];
    const float* w1b = (const float*)d_in[4];
    const float* u1b = (const float*)d_in[5];
    const float* b1b = (const float*)d_in[6];
    const float* w2f = (const float*)d_in[7];
    const float* u2f = (const float*)d_in[8];
    const float* b2f = (const float*)d_in[9];
    const float* w2b = (const float*)d_in[10];
    const float* u2b = (const float*)d_in[11];
    const float* b2b = (const float*)d_in[12];
    const float* w3f = (const float*)d_in[13];
    const float* u3f = (const float*)d_in[14];
    const float* b3f = (const float*)d_in[15];
    const float* w3b = (const float*)d_in[16];
    const float* u3b = (const float*)d_in[17];
    const float* b3b = (const float*)d_in[18];
    const float* d1w = (const float*)d_in[19];
    const float* d1b = (const float*)d_in[20];
    const float* d2w = (const float*)d_in[21];
    const float* d2b = (const float*)d_in[22];
    const float* d3w = (const float*)d_in[23];
    const float* d3b = (const float*)d_in[24];
    const float* bng = (const float*)d_in[25];
    const float* bnb = (const float*)d_in[26];
    const float* bnm = (const float*)d_in[27];
    const float* bnv = (const float*)d_in[28];
    const float* ow  = (const float*)d_in[29];
    const float* ob  = (const float*)d_in[30];

    // Workspace map (bytes). Proven safe footprint (R3): 189,333,504.
    //   h1  f16 (B,T,128) @ 0            .. 62,914,560
    //   h2  f16 (B,T,256) @ 62,914,560   .. 188,743,680
    //     x16 f16 (B,T,128) @ 62,914,560  (dead before lstm2 writes h2)
    //     PB1 @ 125,829,120 (196,608 B)   (dead before lstm2 writes h2)
    //   PB2 @ 188,743,680 (524,288 B)    .. 189,267,968
    //   after lstm2, h1 region reused:
    //     d1o fp32 @ 0 (8,388,608 B)
    //     PD1 @ 8,388,608 (7,864,320 B)
    //     PB3 @ 16,252,928 (2,097,152 B) .. 18,350,080
    char* wsb = (char*)d_ws;
    __half* h1  = (__half*)wsb;
    __half* h2  = (__half*)(wsb + 62914560);
    __half* x16 = (__half*)(wsb + 62914560);
    __half* PB1 = (__half*)(wsb + 125829120);
    __half* PB2 = (__half*)(wsb + 188743680);
    float*  d1o = (float*)wsb;
    __half* PD1 = (__half*)(wsb + 8388608);
    __half* PB3 = (__half*)(wsb + 16252928);

    const dim3 blk(256);
    const dim3 gl(BATCH / 32, 2);   // dir on y

    x_to_f16<<<dim3(122880), blk, 0, stream>>>(x, x16);
    pack_b<126, 128,  64><<<dim3( 384), blk, 0, stream>>>(w1f, u1f, w1b, u1b, PB1);
    pack_b<128, 128, 128><<<dim3(1024), blk, 0, stream>>>(w2f, u2f, w2b, u2b, PB2);

    lstm_mfma<128,  64, false><<<gl, blk, 0, stream>>>(
        x16, PB1, b1f, b1b, h1, nullptr, nullptr);
    lstm_mfma<128, 128, false><<<gl, blk, 0, stream>>>(
        h1, PB2, b2f, b2b, h2, nullptr, nullptr);

    // h1 dead: carve d1o, PD1, PB3 out of its region
    zero_f4<<<dim3(2048), blk, 0, stream>>>(d1o);
    pack_b<256, 256, 256><<<dim3(4096), blk, 0, stream>>>(w3f, u3f, w3b, u3b, PB3);
    pack_d1<<<dim3(15360), blk, 0, stream>>>(d1w, PD1);

    lstm_mfma<256, 256, true><<<gl, blk, 0, stream>>>(
        h2, PB3, b3f, b3b, nullptr, PD1, d1o);

    tail_kernel<<<dim3(BATCH / 16), blk, 0, stream>>>(
        d1o, d1b, d2w, d2b, d3w, d3b, bng, bnb, bnm, bnv, ow, ob, (float*)d_out);
}